// Round 12
// baseline (981.119 us; speedup 1.0000x reference)
//
#include <hip/hip_runtime.h>
#include <math.h>

#define HID    128
#define IN_CH  271
#define SEQ    281
#define NCLS   1854
#define BATCH  256
#define M_TOT  (SEQ * BATCH)          // 71936 = 562 * 128
#define KPAD0  288                    // 271 padded to 9*32
#define NPROD  1686                   // 562 m-blocks * 3 gates

typedef __attribute__((ext_vector_type(8))) short short8;
typedef __attribute__((ext_vector_type(4))) float floatx4;

#define MFMA16(acc, a, b) acc = __builtin_amdgcn_mfma_f32_16x16x32_bf16((a), (b), (acc), 0, 0, 0)

__device__ __forceinline__ unsigned short f2bf(float f) {
    union { float f; unsigned u; } v; v.f = f;
    unsigned u = v.u;
    u += 0x7FFF + ((u >> 16) & 1);        // RNE
    return (unsigned short)(u >> 16);
}

__device__ __forceinline__ float fast_rcp(float x) {
    float r;
    asm("v_rcp_f32 %0, %1" : "=v"(r) : "v"(x));
    return r;
}
__device__ __forceinline__ float fast_sigmoid(float s) {
    return fast_rcp(1.f + __expf(-s));
}
__device__ __forceinline__ float fast_tanh(float s) {
    float e = __expf(-2.f * s);
    return __builtin_fmaf(2.f, fast_rcp(1.f + e), -1.f);
}

// LDS-only barrier: waits ds-ops but does NOT drain vmcnt.
__device__ __forceinline__ void sync_lds() {
    asm volatile("s_waitcnt lgkmcnt(0)\n\ts_barrier" ::: "memory");
}

// Swizzled LDS image (16 rows x 128 bf16, stride 128):
//   (row,k) -> row*128 + (((k>>3)^(row&7))<<3) + (k&7)
__device__ __forceinline__ short8 ldsA_sw(const unsigned short* base, int l15, int kk, int quad) {
    const int chunk = (4 * kk + quad) ^ (l15 & 7);
    return *(const short8*)(base + l15 * 128 + (chunk << 3));
}
__device__ __forceinline__ int sw_idx(int row, int c) {
    return row * 128 + ((((c >> 3) ^ (row & 7)) << 3) | (c & 7));
}

// producer->consumer flag ops (device scope, acquire/release)
__device__ __forceinline__ void wait_flag6(const int* f, int t) {
    while (__hip_atomic_load(f + t, __ATOMIC_ACQUIRE, __HIP_MEMORY_SCOPE_AGENT) < 6)
        __builtin_amdgcn_s_sleep(8);
}

// ---------------------------------------------------------------------------
// Transpose+convert X: X[b][k][t] fp32 -> Abf[(b*281+t)*288 + k] bf16.
// ---------------------------------------------------------------------------
__global__ __launch_bounds__(256) void xt_kernel(
    const float* __restrict__ X, unsigned short* __restrict__ Abf)
{
    const int tb = blockIdx.x;            // 0..4, t-tile of 64
    const int b  = blockIdx.y;
    const int tid = threadIdx.x;
    const int t0 = tb * 64;
    const float* __restrict__ Xb = X + (size_t)b * (IN_CH * SEQ);

    __shared__ float Xl[32][65];

    for (int kc = 0; kc < KPAD0 / 32; ++kc) {
#pragma unroll
        for (int r = 0; r < 8; ++r) {
            int e = tid + 256 * r;
            int kk = e >> 6, tt = e & 63;
            int k = kc * 32 + kk, t = t0 + tt;
            Xl[kk][tt] = (k < IN_CH && t < SEQ) ? Xb[k * SEQ + t] : 0.f;
        }
        __syncthreads();
        {
            int tt = tid >> 2, part = tid & 3;
            int t = t0 + tt;
            if (t < SEQ) {
                union { unsigned short s[8]; uint4 v; } u;
#pragma unroll
                for (int i = 0; i < 8; ++i) u.s[i] = f2bf(Xl[part * 8 + i][tt]);
                *(uint4*)(Abf + ((size_t)b * SEQ + t) * KPAD0 + kc * 32 + part * 8) = u.v;
            }
        }
        __syncthreads();
    }
}

// ---------------------------------------------------------------------------
// Weight transpose+convert + flag zeroing. grid (12, 32).
// ---------------------------------------------------------------------------
__global__ __launch_bounds__(256) void wt_kernel(
    const float* __restrict__ Wr0, const float* __restrict__ Wu0, const float* __restrict__ Wo0,
    const float* __restrict__ Wr1, const float* __restrict__ Wu1, const float* __restrict__ Wo1,
    unsigned short* __restrict__ Wt0, unsigned short* __restrict__ Wh0,
    unsigned short* __restrict__ Wx1, unsigned short* __restrict__ Wh1,
    int* __restrict__ flags)
{
    const int blk  = blockIdx.x;
    const int kind = blk / 3, g = blk % 3;
    const int tid  = threadIdx.x;
    const int n0   = blockIdx.y * 4;

    if (blk == 0 && blockIdx.y == 0) {     // zero the 281 t-flags (+pad)
        for (int i = tid; i < 512; i += 256) flags[i] = 0;
    }

    const float* __restrict__ W =
        (kind <= 1) ? ((g == 0) ? Wr0 : (g == 1) ? Wu0 : Wo0)
                    : ((g == 0) ? Wr1 : (g == 1) ? Wu1 : Wo1);

    if (kind == 0) {
        unsigned short* __restrict__ out = Wt0 + (size_t)g * HID * KPAD0;
        for (int n = n0; n < n0 + 4; ++n)
            for (int k = tid; k < KPAD0; k += 256) {
                float v = (k < IN_CH) ? W[(size_t)k * HID + n] : 0.f;
                out[(size_t)n * KPAD0 + k] = f2bf(v);
            }
    } else {
        const int rbase = (kind == 1) ? IN_CH : (kind == 2) ? 0 : HID;
        unsigned short* __restrict__ out =
            ((kind == 1) ? Wh0 : (kind == 2) ? Wx1 : Wh1) + (size_t)g * HID * HID;
        for (int n = n0; n < n0 + 4; ++n)
            for (int k = tid; k < HID; k += 256)
                out[(size_t)n * HID + k] = f2bf(W[(size_t)(rbase + k) * HID + n]);
    }
}

// ===========================================================================
// MEGAKERNEL: blocks 0..15 = GRU consumer (frozen R11 loop + flag waits);
// blocks 16.. = GEMM producers (one 128x128 tile, t-ascending, signal
// flag[tt] with release atomicAdd; 6 signals per t = 2 b-halves x 3 gates).
// Deadlock-free: producers wait on nothing; 16 spinners leave 240 CUs free.
// ===========================================================================
__global__ __launch_bounds__(512, 1) void mega_kernel(
    const unsigned short* __restrict__ Wh0,
    const unsigned short* __restrict__ Wx1,
    const unsigned short* __restrict__ Wh1,
    float* __restrict__ XG,
    const float* __restrict__ br1, const float* __restrict__ bu1, const float* __restrict__ bo1,
    float* __restrict__ H1fin,
    const unsigned short* __restrict__ Abf,
    const unsigned short* __restrict__ Wt0,
    const float* __restrict__ br0, const float* __restrict__ bu0, const float* __restrict__ bo0,
    int* __restrict__ flags)
{
    __shared__ __attribute__((aligned(16))) unsigned short smem[10240];  // 20 KB

    const int tid  = threadIdx.x;
    const int wv   = tid >> 6;
    const int lane = tid & 63;
    const int l15  = lane & 15;
    const int quad = lane >> 4;

    if (blockIdx.x < 16) {
        // ================= GRU consumer role (R11, frozen) =================
        unsigned short* Hbf0 = smem;
        unsigned short* Rbf0 = smem + 2048;
        unsigned short* Hbf1 = smem + 4096;
        unsigned short* Rbf1 = smem + 6144;

        const int b0 = blockIdx.x * 16;
        const int c  = wv * 16 + l15;

        short8 B0r[4], B0u[4], B0o[4], Bxr[4], Bxu[4], Bxo[4], B1r[4], B1u[4], B1o[4];
#pragma unroll
        for (int kk = 0; kk < 4; ++kk) {
            const size_t off = (size_t)(wv * 16 + l15) * HID + kk * 32 + quad * 8;
            B0r[kk] = *(const short8*)(Wh0 + off);
            B0u[kk] = *(const short8*)(Wh0 + (size_t)128 * HID + off);
            B0o[kk] = *(const short8*)(Wh0 + (size_t)256 * HID + off);
            Bxr[kk] = *(const short8*)(Wx1 + off);
            Bxu[kk] = *(const short8*)(Wx1 + (size_t)128 * HID + off);
            Bxo[kk] = *(const short8*)(Wx1 + (size_t)256 * HID + off);
            B1r[kk] = *(const short8*)(Wh1 + off);
            B1u[kk] = *(const short8*)(Wh1 + (size_t)128 * HID + off);
            B1o[kk] = *(const short8*)(Wh1 + (size_t)256 * HID + off);
        }

        for (int idx = tid; idx < 8192; idx += 512) smem[idx] = 0;

        float h0c[4], h1c[4];
#pragma unroll
        for (int i = 0; i < 4; ++i) { h0c[i] = 0.f; h1c[i] = 0.f; }

        const float br1c = br1[c], bu1c = bu1[c], bo1c = bo1[c];

        int sidx[4];
#pragma unroll
        for (int j = 0; j < 4; ++j) sidx[j] = sw_idx(quad * 4 + j, c);

        const int XGSTEP = 384 * BATCH;
        const float* xgp = XG + (size_t)c * BATCH + b0 + quad * 4;
        wait_flag6(flags, 0);
        float4 xr4 = *(const float4*)(xgp);
        float4 xu4 = *(const float4*)(xgp + (size_t)128 * BATCH);
        float4 xo4 = *(const float4*)(xgp + (size_t)256 * BATCH);
        xgp += XGSTEP;
        __syncthreads();

        for (int t = 0; t < SEQ; ++t) {
            float4 nr4, nu4, no4;
            const bool pf = (t + 1 < SEQ);
            if (pf) {
                wait_flag6(flags, t + 1);
                nr4 = *(const float4*)(xgp);
                nu4 = *(const float4*)(xgp + (size_t)128 * BATCH);
                no4 = *(const float4*)(xgp + (size_t)256 * BATCH);
                xgp += XGSTEP;
            }

            // ---- P1: L0 r,u  +  L1 r,u partials from h1(t-1)
            floatx4 ar = (floatx4)0.f, au = (floatx4)0.f;
            floatx4 a1r = (floatx4)0.f, a1u = (floatx4)0.f;
#pragma unroll
            for (int kk = 0; kk < 4; ++kk) {
                short8 a0 = ldsA_sw(Hbf0, l15, kk, quad);
                short8 a1 = ldsA_sw(Hbf1, l15, kk, quad);
                MFMA16(ar,  a0, B0r[kk]);
                MFMA16(au,  a0, B0u[kk]);
                MFMA16(a1r, a1, B1r[kk]);
                MFMA16(a1u, a1, B1u[kk]);
            }
            float ug0[4];
#pragma unroll
            for (int j = 0; j < 4; ++j) {
                float rg = fast_sigmoid(ar[j] + xr4[j]);
                ug0[j] = fast_sigmoid(au[j] + xu4[j]);
                Rbf0[sidx[j]] = f2bf(rg * h0c[j]);
            }
            sync_lds();

            // ---- P2: L0 o + h0 update
            floatx4 ao = (floatx4)0.f;
#pragma unroll
            for (int kk = 0; kk < 4; ++kk)
                MFMA16(ao, ldsA_sw(Rbf0, l15, kk, quad), B0o[kk]);
#pragma unroll
            for (int j = 0; j < 4; ++j) {
                float og = fast_tanh(ao[j] + xo4[j]);
                h0c[j] = h0c[j] + ug0[j] * (og - h0c[j]);
                Hbf0[sidx[j]] = f2bf(h0c[j]);
            }
            sync_lds();

            // ---- P3: L1 x-contributions from h0(t); finish r1,u1
            floatx4 axo = (floatx4)0.f;
#pragma unroll
            for (int kk = 0; kk < 4; ++kk) {
                short8 a0 = ldsA_sw(Hbf0, l15, kk, quad);
                MFMA16(a1r, a0, Bxr[kk]);
                MFMA16(a1u, a0, Bxu[kk]);
                MFMA16(axo, a0, Bxo[kk]);
            }
            float ug1[4];
#pragma unroll
            for (int j = 0; j < 4; ++j) {
                float rg1 = fast_sigmoid(a1r[j] + br1c);
                ug1[j] = fast_sigmoid(a1u[j] + bu1c);
                Rbf1[sidx[j]] = f2bf(rg1 * h1c[j]);
            }
            sync_lds();

            // ---- P4: L1 o + h1 update
#pragma unroll
            for (int kk = 0; kk < 4; ++kk)
                MFMA16(axo, ldsA_sw(Rbf1, l15, kk, quad), B1o[kk]);
#pragma unroll
            for (int j = 0; j < 4; ++j) {
                float og1 = fast_tanh(axo[j] + bo1c);
                h1c[j] = h1c[j] + ug1[j] * (og1 - h1c[j]);
                Hbf1[sidx[j]] = f2bf(h1c[j]);
            }
            if (pf) { xr4 = nr4; xu4 = nu4; xo4 = no4; }
            sync_lds();
        }

#pragma unroll
        for (int j = 0; j < 4; ++j)
            H1fin[(size_t)(b0 + quad * 4 + j) * HID + c] = h1c[j];

    } else {
        // ================= GEMM producer role =================
        // q t-ascending: mblock = q/3 (tt = mblock>>1, b-half = mblock&1),
        // gate = q%3. One 128x128 tile, K=288, 8 waves.
        const int q      = blockIdx.x - 16;
        const int mblock = q / 3;
        const int g      = q - 3 * mblock;
        const int tt     = mblock >> 1;
        const int b0m    = (mblock & 1) * 128;

        const float* __restrict__ bias = (g == 0) ? br0 : (g == 1) ? bu0 : bo0;
        const unsigned short* __restrict__ B = Wt0 + (size_t)g * HID * KPAD0;

        unsigned short* As = smem;          // 128*40
        unsigned short* Bs = smem + 5120;   // 128*40

        const int mq = wv >> 1;             // 0..3: 32-row strip
        const int nq = wv & 1;              // 0..1: 64-col half

        floatx4 acc[2][4];
#pragma unroll
        for (int im = 0; im < 2; ++im)
#pragma unroll
            for (int in = 0; in < 4; ++in) acc[im][in] = (floatx4)0.f;

        const int r = tid >> 2, part = tid & 3;   // one A chunk + one B chunk per thread

        for (int kt = 0; kt < KPAD0 / 32; ++kt) {
            if (kt) __syncthreads();
            const int kb = kt * 32;
            uint4 va = *(const uint4*)(Abf + ((size_t)(b0m + r) * SEQ + tt) * KPAD0 + kb + part * 8);
            uint4 vb = *(const uint4*)(B + (size_t)r * KPAD0 + kb + part * 8);
            *(uint4*)(As + r * 40 + part * 8) = va;
            *(uint4*)(Bs + r * 40 + part * 8) = vb;
            __syncthreads();

            short8 af[2], bf[4];
#pragma unroll
            for (int im = 0; im < 2; ++im)
                af[im] = *(const short8*)(As + (mq * 32 + im * 16 + l15) * 40 + quad * 8);
#pragma unroll
            for (int in = 0; in < 4; ++in)
                bf[in] = *(const short8*)(Bs + (nq * 64 + in * 16 + l15) * 40 + quad * 8);
#pragma unroll
            for (int im = 0; im < 2; ++im)
#pragma unroll
                for (int in = 0; in < 4; ++in)
                    MFMA16(acc[im][in], af[im], bf[in]);
        }

        float bv[4];
#pragma unroll
        for (int in = 0; in < 4; ++in) bv[in] = bias[nq * 64 + in * 16 + l15];
#pragma unroll
        for (int im = 0; im < 2; ++im) {
            const int bb = b0m + mq * 32 + im * 16 + quad * 4;
#pragma unroll
            for (int in = 0; in < 4; ++in) {
                const int n = nq * 64 + in * 16 + l15;
                float4 v = make_float4(acc[im][in][0] + bv[in], acc[im][in][1] + bv[in],
                                       acc[im][in][2] + bv[in], acc[im][in][3] + bv[in]);
                *(float4*)(XG + ((size_t)tt * 384 + g * HID + n) * BATCH + bb) = v;
            }
        }

        __syncthreads();                    // drains vmcnt (stores complete)
        if (tid == 0)
            __hip_atomic_fetch_add(flags + tt, 1, __ATOMIC_RELEASE, __HIP_MEMORY_SCOPE_AGENT);
    }
}

// ---------------------------------------------------------------------------
// Classifier: out[b][c] = bfc[c] + sum_k H1[b][k] * Wfc[k][c]
// ---------------------------------------------------------------------------
__global__ __launch_bounds__(256) void cls_kernel(
    const float* __restrict__ H1, const float* __restrict__ Wfc,
    const float* __restrict__ bfc, float* __restrict__ out)
{
    const int b = blockIdx.x;
    const int tid = threadIdx.x;
    __shared__ float h[HID];
    if (tid < HID) h[tid] = H1[(size_t)b * HID + tid];
    __syncthreads();
    for (int c = tid; c < NCLS; c += 256) {
        float a = bfc[c];
#pragma unroll 8
        for (int k = 0; k < HID; ++k)
            a += h[k] * Wfc[(size_t)k * NCLS + c];
        out[(size_t)b * NCLS + c] = a;
    }
}

// ---------------------------------------------------------------------------
extern "C" void kernel_launch(void* const* d_in, const int* in_sizes, int n_in,
                              void* d_out, int out_size, void* d_ws, size_t ws_size,
                              hipStream_t stream)
{
    const float* X   = (const float*)d_in[0];
    const float* Wr0 = (const float*)d_in[1];
    const float* br0 = (const float*)d_in[2];
    const float* Wu0 = (const float*)d_in[3];
    const float* bu0 = (const float*)d_in[4];
    const float* Wo0 = (const float*)d_in[5];
    const float* bo0 = (const float*)d_in[6];
    const float* Wr1 = (const float*)d_in[7];
    const float* br1 = (const float*)d_in[8];
    const float* Wu1 = (const float*)d_in[9];
    const float* bu1 = (const float*)d_in[10];
    const float* Wo1 = (const float*)d_in[11];
    const float* bo1 = (const float*)d_in[12];
    const float* Wfc = (const float*)d_in[13];
    const float* bfc = (const float*)d_in[14];
    float* out = (float*)d_out;

    // workspace:
    //   XG  fp32 [281*384*256]   110,493,696 B   ([t][chan][b])
    //   Abf bf16 [M_TOT*288]      41,435,136 B   (H1fin aliases: dead after mega)
    //   Wt0 bf16 [3*128*288]         221,184 B
    //   Wh0/Wx1/Wh1 bf16 [384*128]    98,304 B each
    //   flags int[512]                 2,048 B
    char* ws = (char*)d_ws;
    float*          XG    = (float*)ws;
    unsigned short* Abf   = (unsigned short*)(ws + (size_t)M_TOT * 384 * 4);
    float*          H1fin = (float*)Abf;        // alias: Abf dead after producers
    unsigned short* Wt0   = (unsigned short*)(ws + (size_t)M_TOT * 384 * 4 + (size_t)M_TOT * KPAD0 * 2);
    unsigned short* Wh0   = Wt0 + (size_t)3 * HID * KPAD0;
    unsigned short* Wx1   = Wh0 + (size_t)384 * HID;
    unsigned short* Wh1   = Wx1 + (size_t)384 * HID;
    int*            flags = (int*)(Wh1 + (size_t)384 * HID);

    wt_kernel<<<dim3(12, 32), 256, 0, stream>>>(Wr0, Wu0, Wo0, Wr1, Wu1, Wo1,
                                                Wt0, Wh0, Wx1, Wh1, flags);
    xt_kernel<<<dim3(5, BATCH), 256, 0, stream>>>(X, Abf);
    mega_kernel<<<dim3(16 + NPROD), 512, 0, stream>>>(
        Wh0, Wx1, Wh1, XG, br1, bu1, bo1, H1fin,
        Abf, Wt0, br0, bu0, bo0, flags);
    cls_kernel<<<dim3(BATCH), 256, 0, stream>>>(H1fin, Wfc, bfc, out);
}

// Round 13
// 790.594 us; speedup vs baseline: 1.2410x; 1.2410x over previous
//
#include <hip/hip_runtime.h>
#include <math.h>

#define HID    128
#define IN_CH  271
#define SEQ    281
#define NCLS   1854
#define BATCH  256
#define M_TOT  (SEQ * BATCH)          // 71936 = 562 * 128
#define KPAD0  288                    // 271 padded to 9*32

typedef __attribute__((ext_vector_type(8))) short short8;
typedef __attribute__((ext_vector_type(4))) float floatx4;

#define MFMA16(acc, a, b) acc = __builtin_amdgcn_mfma_f32_16x16x32_bf16((a), (b), (acc), 0, 0, 0)

__device__ __forceinline__ unsigned short f2bf(float f) {
    union { float f; unsigned u; } v; v.f = f;
    unsigned u = v.u;
    u += 0x7FFF + ((u >> 16) & 1);        // RNE
    return (unsigned short)(u >> 16);
}

__device__ __forceinline__ float fast_rcp(float x) {
    float r;
    asm("v_rcp_f32 %0, %1" : "=v"(r) : "v"(x));
    return r;
}
__device__ __forceinline__ float fast_sigmoid(float s) {
    return fast_rcp(1.f + __expf(-s));
}
// tanh(x) = 2/(1+e^{-2x}) - 1 ; exp limits (inf/0) give exactly -1/+1, branch-free
__device__ __forceinline__ float fast_tanh(float s) {
    float e = __expf(-2.f * s);
    return __builtin_fmaf(2.f, fast_rcp(1.f + e), -1.f);
}

// LDS-only barrier: waits ds-ops but does NOT drain vmcnt.
__device__ __forceinline__ void sync_lds() {
    asm volatile("s_waitcnt lgkmcnt(0)\n\ts_barrier" ::: "memory");
}

// Swizzled LDS image (16 rows x 128 bf16, stride 128):
//   (row,k) -> row*128 + (((k>>3)^(row&7))<<3) + (k&7)
__device__ __forceinline__ short8 ldsA_sw(const unsigned short* base, int l15, int kk, int quad) {
    const int chunk = (4 * kk + quad) ^ (l15 & 7);
    return *(const short8*)(base + l15 * 128 + (chunk << 3));
}
__device__ __forceinline__ int sw_idx(int row, int c) {
    return row * 128 + ((((c >> 3) ^ (row & 7)) << 3) | (c & 7));
}

// ---------------------------------------------------------------------------
// Transpose+convert X: X[b][k][t] fp32 -> Abf[(b*281+t)*288 + k] bf16.
// ---------------------------------------------------------------------------
__global__ __launch_bounds__(256) void xt_kernel(
    const float* __restrict__ X, unsigned short* __restrict__ Abf)
{
    const int tb = blockIdx.x;            // 0..4, t-tile of 64
    const int b  = blockIdx.y;
    const int tid = threadIdx.x;
    const int t0 = tb * 64;
    const float* __restrict__ Xb = X + (size_t)b * (IN_CH * SEQ);

    __shared__ float Xl[32][65];

    for (int kc = 0; kc < KPAD0 / 32; ++kc) {
#pragma unroll
        for (int r = 0; r < 8; ++r) {
            int e = tid + 256 * r;
            int kk = e >> 6, tt = e & 63;
            int k = kc * 32 + kk, t = t0 + tt;
            Xl[kk][tt] = (k < IN_CH && t < SEQ) ? Xb[k * SEQ + t] : 0.f;
        }
        __syncthreads();
        {
            int tt = tid >> 2, part = tid & 3;
            int t = t0 + tt;
            if (t < SEQ) {
                union { unsigned short s[8]; uint4 v; } u;
#pragma unroll
                for (int i = 0; i < 8; ++i) u.s[i] = f2bf(Xl[part * 8 + i][tt]);
                *(uint4*)(Abf + ((size_t)b * SEQ + t) * KPAD0 + kc * 32 + part * 8) = u.v;
            }
        }
        __syncthreads();
    }
}

// ---------------------------------------------------------------------------
// Weight transpose+convert. grid (12, 32), blockIdx.y = n-slice of 4.
// blk 0..2 : Wt0 [n][288]        = W0g[k][n], k<271 (gemm B, layer0 x-part)
// blk 3..5 : Wh0 [g*128+n][128]  = W0g[271+k][n]     (gru, layer0 h-part)
// blk 6..8 : Wx1 [g*128+n][128]  = W1g[k][n]         (gru, layer1 x-part)
// blk 9..11: Wh1 [g*128+n][128]  = W1g[128+k][n]     (gru, layer1 h-part)
// ---------------------------------------------------------------------------
__global__ __launch_bounds__(256) void wt_kernel(
    const float* __restrict__ Wr0, const float* __restrict__ Wu0, const float* __restrict__ Wo0,
    const float* __restrict__ Wr1, const float* __restrict__ Wu1, const float* __restrict__ Wo1,
    unsigned short* __restrict__ Wt0, unsigned short* __restrict__ Wh0,
    unsigned short* __restrict__ Wx1, unsigned short* __restrict__ Wh1)
{
    const int blk  = blockIdx.x;
    const int kind = blk / 3, g = blk % 3;
    const int tid  = threadIdx.x;
    const int n0   = blockIdx.y * 4;

    const float* __restrict__ W =
        (kind <= 1) ? ((g == 0) ? Wr0 : (g == 1) ? Wu0 : Wo0)
                    : ((g == 0) ? Wr1 : (g == 1) ? Wu1 : Wo1);

    if (kind == 0) {
        unsigned short* __restrict__ out = Wt0 + (size_t)g * HID * KPAD0;
        for (int n = n0; n < n0 + 4; ++n)
            for (int k = tid; k < KPAD0; k += 256) {
                float v = (k < IN_CH) ? W[(size_t)k * HID + n] : 0.f;
                out[(size_t)n * KPAD0 + k] = f2bf(v);
            }
    } else {
        const int rbase = (kind == 1) ? IN_CH : (kind == 2) ? 0 : HID;
        unsigned short* __restrict__ out =
            ((kind == 1) ? Wh0 : (kind == 2) ? Wx1 : Wh1) + (size_t)g * HID * HID;
        for (int n = n0; n < n0 + 4; ++n)
            for (int k = tid; k < HID; k += 256)
                out[(size_t)n * HID + k] = f2bf(W[(size_t)(rbase + k) * HID + n]);
    }
}

// ---------------------------------------------------------------------------
// bf16 MFMA GEMM (layer-0 x-contributions only), register-pipelined:
// next K-tile is loaded into registers while MFMAs consume the current LDS
// tile; both barriers are LDS-only (no vmcnt drain — the R12 lesson is that
// __syncthreads' vmcnt(0) exposed the full global latency per K-step).
// Logical row m' = t*256 + b; tile m0 = blk*128 -> tt = m0>>8, b0m = m0&255.
// Output: XG[(tt*384 + g*128 + n)*256 + b]  (fp32), float4 stores.
// ---------------------------------------------------------------------------
__global__ __launch_bounds__(256) void gemm_xg(
    const unsigned short* __restrict__ A,
    const unsigned short* __restrict__ Wt,
    const float* __restrict__ br, const float* __restrict__ bu, const float* __restrict__ bo,
    float* __restrict__ XG)
{
    const int g = blockIdx.y;
    const float* __restrict__ bias = (g == 0) ? br : (g == 1) ? bu : bo;
    const unsigned short* __restrict__ B = Wt + (size_t)g * HID * KPAD0;

    __shared__ unsigned short As[128 * 40];
    __shared__ unsigned short Bs[128 * 40];

    const int tid   = threadIdx.x;
    const int lane  = tid & 63;
    const int wave  = tid >> 6;
    const int l15   = lane & 15;
    const int quad  = lane >> 4;
    const int mhalf = wave >> 1;
    const int nhalf = wave & 1;
    const int m0    = blockIdx.x * 128;
    const int tt    = m0 >> 8;
    const int b0m   = m0 & 255;

    floatx4 acc[4][4];
#pragma unroll
    for (int im = 0; im < 4; ++im)
#pragma unroll
        for (int in = 0; in < 4; ++in) acc[im][in] = (floatx4)0.f;

    const int r0 = tid >> 2, p0 = tid & 3;
    const int r1 = (tid + 256) >> 2, p1 = tid & 3;

    const size_t arow0 = ((size_t)(b0m + r0) * SEQ + tt) * KPAD0;
    const size_t arow1 = ((size_t)(b0m + r1) * SEQ + tt) * KPAD0;
    const size_t brow0 = (size_t)r0 * KPAD0;
    const size_t brow1 = (size_t)r1 * KPAD0;

    // prefetch K-tile 0 into registers
    uint4 va0 = *(const uint4*)(A + arow0 + p0 * 8);
    uint4 va1 = *(const uint4*)(A + arow1 + p1 * 8);
    uint4 vb0 = *(const uint4*)(B + brow0 + p0 * 8);
    uint4 vb1 = *(const uint4*)(B + brow1 + p1 * 8);

    const int ks = KPAD0 / 32;
    for (int kt = 0; kt < ks; ++kt) {
        if (kt) sync_lds();                   // prev iter's LDS reads done
        *(uint4*)(As + r0 * 40 + p0 * 8) = va0;   // compiler waits vmcnt here
        *(uint4*)(As + r1 * 40 + p1 * 8) = va1;
        *(uint4*)(Bs + r0 * 40 + p0 * 8) = vb0;
        *(uint4*)(Bs + r1 * 40 + p1 * 8) = vb1;
        sync_lds();

        // issue next K-tile's loads — land while MFMAs run
        if (kt + 1 < ks) {
            const int kb = (kt + 1) * 32;
            va0 = *(const uint4*)(A + arow0 + kb + p0 * 8);
            va1 = *(const uint4*)(A + arow1 + kb + p1 * 8);
            vb0 = *(const uint4*)(B + brow0 + kb + p0 * 8);
            vb1 = *(const uint4*)(B + brow1 + kb + p1 * 8);
        }

        short8 af[4], bf[4];
#pragma unroll
        for (int im = 0; im < 4; ++im)
            af[im] = *(const short8*)(As + (mhalf * 64 + im * 16 + l15) * 40 + quad * 8);
#pragma unroll
        for (int in = 0; in < 4; ++in)
            bf[in] = *(const short8*)(Bs + (nhalf * 64 + in * 16 + l15) * 40 + quad * 8);
#pragma unroll
        for (int im = 0; im < 4; ++im)
#pragma unroll
            for (int in = 0; in < 4; ++in)
                MFMA16(acc[im][in], af[im], bf[in]);
    }

    float bv[4];
#pragma unroll
    for (int in = 0; in < 4; ++in) bv[in] = bias[nhalf * 64 + in * 16 + l15];
#pragma unroll
    for (int im = 0; im < 4; ++im) {
        const int bb = b0m + mhalf * 64 + im * 16 + quad * 4;
#pragma unroll
        for (int in = 0; in < 4; ++in) {
            const int n = nhalf * 64 + in * 16 + l15;
            float4 v = make_float4(acc[im][in][0] + bv[in], acc[im][in][1] + bv[in],
                                   acc[im][in][2] + bv[in], acc[im][in][3] + bv[in]);
            *(float4*)(XG + ((size_t)tt * 384 + g * HID + n) * BATCH + bb) = v;
        }
    }
}

// ---------------------------------------------------------------------------
// FUSED 2-layer GRU — R11 FROZEN (best measured: 464 µs). 4-phase, XOR-
// swizzled LDS, 36 B-fragments hoisted as MFMA operands, 4 LDS-only
// barriers/step. Do not merge phases (R9), do not add classifier tail (R10),
// do not split b128 reads (R8), do not put flag-waits in the loop (R12).
// ---------------------------------------------------------------------------
__global__ __launch_bounds__(512, 1) void gru_fused(
    const unsigned short* __restrict__ Wh0,
    const unsigned short* __restrict__ Wx1,
    const unsigned short* __restrict__ Wh1,
    const float* __restrict__ XG,
    const float* __restrict__ br1, const float* __restrict__ bu1, const float* __restrict__ bo1,
    float* __restrict__ H1fin)
{
    const int b0   = blockIdx.x * 16;
    const int tid  = threadIdx.x;
    const int w    = tid >> 6;        // 0..7
    const int lane = tid & 63;
    const int l15  = lane & 15;
    const int quad = lane >> 4;
    const int c    = w * 16 + l15;    // this thread's column 0..127

    __shared__ __attribute__((aligned(16))) unsigned short Hbf0[16 * 128];
    __shared__ __attribute__((aligned(16))) unsigned short Rbf0[16 * 128];
    __shared__ __attribute__((aligned(16))) unsigned short Hbf1[16 * 128];
    __shared__ __attribute__((aligned(16))) unsigned short Rbf1[16 * 128];

    // hoisted weight B-fragments: 9 (layer,gate) tiles x 4 k-steps
    short8 B0r[4], B0u[4], B0o[4], Bxr[4], Bxu[4], Bxo[4], B1r[4], B1u[4], B1o[4];
#pragma unroll
    for (int kk = 0; kk < 4; ++kk) {
        const size_t off = (size_t)(w * 16 + l15) * HID + kk * 32 + quad * 8;
        B0r[kk] = *(const short8*)(Wh0 + off);
        B0u[kk] = *(const short8*)(Wh0 + (size_t)128 * HID + off);
        B0o[kk] = *(const short8*)(Wh0 + (size_t)256 * HID + off);
        Bxr[kk] = *(const short8*)(Wx1 + off);
        Bxu[kk] = *(const short8*)(Wx1 + (size_t)128 * HID + off);
        Bxo[kk] = *(const short8*)(Wx1 + (size_t)256 * HID + off);
        B1r[kk] = *(const short8*)(Wh1 + off);
        B1u[kk] = *(const short8*)(Wh1 + (size_t)128 * HID + off);
        B1o[kk] = *(const short8*)(Wh1 + (size_t)256 * HID + off);
    }

    for (int idx = tid; idx < 16 * 128; idx += 512) {
        Hbf0[idx] = 0; Rbf0[idx] = 0; Hbf1[idx] = 0; Rbf1[idx] = 0;
    }

    float h0c[4], h1c[4];
#pragma unroll
    for (int i = 0; i < 4; ++i) { h0c[i] = 0.f; h1c[i] = 0.f; }

    const float br1c = br1[c], bu1c = bu1[c], bo1c = bo1[c];

    // swizzled store indices for this thread's 4 rows (col c fixed)
    int sidx[4];
#pragma unroll
    for (int j = 0; j < 4; ++j) sidx[j] = sw_idx(quad * 4 + j, c);

    const int XGSTEP = 384 * BATCH;
    const float* xgp = XG + (size_t)c * BATCH + b0 + quad * 4;   // t=0 row
    float4 xr4 = *(const float4*)(xgp);
    float4 xu4 = *(const float4*)(xgp + (size_t)128 * BATCH);
    float4 xo4 = *(const float4*)(xgp + (size_t)256 * BATCH);
    xgp += XGSTEP;
    __syncthreads();

    for (int t = 0; t < SEQ; ++t) {
        // prefetch xg(t+1) — lands during this step's compute
        float4 nr4, nu4, no4;
        const bool pf = (t + 1 < SEQ);
        if (pf) {
            nr4 = *(const float4*)(xgp);
            nu4 = *(const float4*)(xgp + (size_t)128 * BATCH);
            no4 = *(const float4*)(xgp + (size_t)256 * BATCH);
            xgp += XGSTEP;
        }

        // ---- P1: L0 r,u  +  L1 r,u partials from h1(t-1)
        floatx4 ar = (floatx4)0.f, au = (floatx4)0.f;
        floatx4 a1r = (floatx4)0.f, a1u = (floatx4)0.f;
#pragma unroll
        for (int kk = 0; kk < 4; ++kk) {
            short8 a0 = ldsA_sw(Hbf0, l15, kk, quad);
            short8 a1 = ldsA_sw(Hbf1, l15, kk, quad);
            MFMA16(ar,  a0, B0r[kk]);
            MFMA16(au,  a0, B0u[kk]);
            MFMA16(a1r, a1, B1r[kk]);
            MFMA16(a1u, a1, B1u[kk]);
        }
        float ug0[4];
#pragma unroll
        for (int j = 0; j < 4; ++j) {
            float rg = fast_sigmoid(ar[j] + xr4[j]);
            ug0[j] = fast_sigmoid(au[j] + xu4[j]);
            Rbf0[sidx[j]] = f2bf(rg * h0c[j]);
        }
        sync_lds();

        // ---- P2: L0 o + h0 update
        floatx4 ao = (floatx4)0.f;
#pragma unroll
        for (int kk = 0; kk < 4; ++kk)
            MFMA16(ao, ldsA_sw(Rbf0, l15, kk, quad), B0o[kk]);
#pragma unroll
        for (int j = 0; j < 4; ++j) {
            float og = fast_tanh(ao[j] + xo4[j]);
            h0c[j] = h0c[j] + ug0[j] * (og - h0c[j]);
            Hbf0[sidx[j]] = f2bf(h0c[j]);
        }
        sync_lds();

        // ---- P3: L1 x-contributions from h0(t); finish r1,u1
        floatx4 axo = (floatx4)0.f;
#pragma unroll
        for (int kk = 0; kk < 4; ++kk) {
            short8 a0 = ldsA_sw(Hbf0, l15, kk, quad);
            MFMA16(a1r, a0, Bxr[kk]);
            MFMA16(a1u, a0, Bxu[kk]);
            MFMA16(axo, a0, Bxo[kk]);
        }
        float ug1[4];
#pragma unroll
        for (int j = 0; j < 4; ++j) {
            float rg1 = fast_sigmoid(a1r[j] + br1c);
            ug1[j] = fast_sigmoid(a1u[j] + bu1c);
            Rbf1[sidx[j]] = f2bf(rg1 * h1c[j]);
        }
        sync_lds();

        // ---- P4: L1 o + h1 update
#pragma unroll
        for (int kk = 0; kk < 4; ++kk)
            MFMA16(axo, ldsA_sw(Rbf1, l15, kk, quad), B1o[kk]);
#pragma unroll
        for (int j = 0; j < 4; ++j) {
            float og1 = fast_tanh(axo[j] + bo1c);
            h1c[j] = h1c[j] + ug1[j] * (og1 - h1c[j]);
            Hbf1[sidx[j]] = f2bf(h1c[j]);
        }
        if (pf) { xr4 = nr4; xu4 = nu4; xo4 = no4; }
        sync_lds();
    }

#pragma unroll
    for (int j = 0; j < 4; ++j)
        H1fin[(size_t)(b0 + quad * 4 + j) * HID + c] = h1c[j];
}

// ---------------------------------------------------------------------------
// Classifier: 4 batches per block (grid 64) — Wfc re-read 4x less.
// out[b][c] = bfc[c] + sum_k H1[b][k] * Wfc[k][c]
// ---------------------------------------------------------------------------
__global__ __launch_bounds__(256) void cls_kernel(
    const float* __restrict__ H1, const float* __restrict__ Wfc,
    const float* __restrict__ bfc, float* __restrict__ out)
{
    const int b0 = blockIdx.x * 4;
    const int tid = threadIdx.x;
    __shared__ float h[4][HID];
    if (tid < 2 * HID) {
        int r = tid >> 7, k = tid & 127;
        h[r][k]     = H1[(size_t)(b0 + r) * HID + k];
        h[r + 2][k] = H1[(size_t)(b0 + r + 2) * HID + k];
    }
    __syncthreads();
    for (int c = tid; c < NCLS; c += 256) {
        float bv = bfc[c];
        float a0 = bv, a1 = bv, a2 = bv, a3 = bv;
#pragma unroll 4
        for (int k = 0; k < HID; ++k) {
            float wv = Wfc[(size_t)k * NCLS + c];
            a0 += h[0][k] * wv;
            a1 += h[1][k] * wv;
            a2 += h[2][k] * wv;
            a3 += h[3][k] * wv;
        }
        out[(size_t)(b0 + 0) * NCLS + c] = a0;
        out[(size_t)(b0 + 1) * NCLS + c] = a1;
        out[(size_t)(b0 + 2) * NCLS + c] = a2;
        out[(size_t)(b0 + 3) * NCLS + c] = a3;
    }
}

// ---------------------------------------------------------------------------
extern "C" void kernel_launch(void* const* d_in, const int* in_sizes, int n_in,
                              void* d_out, int out_size, void* d_ws, size_t ws_size,
                              hipStream_t stream)
{
    const float* X   = (const float*)d_in[0];
    const float* Wr0 = (const float*)d_in[1];
    const float* br0 = (const float*)d_in[2];
    const float* Wu0 = (const float*)d_in[3];
    const float* bu0 = (const float*)d_in[4];
    const float* Wo0 = (const float*)d_in[5];
    const float* bo0 = (const float*)d_in[6];
    const float* Wr1 = (const float*)d_in[7];
    const float* br1 = (const float*)d_in[8];
    const float* Wu1 = (const float*)d_in[9];
    const float* bu1 = (const float*)d_in[10];
    const float* Wo1 = (const float*)d_in[11];
    const float* bo1 = (const float*)d_in[12];
    const float* Wfc = (const float*)d_in[13];
    const float* bfc = (const float*)d_in[14];
    float* out = (float*)d_out;

    // workspace:
    //   XG  fp32 [281*384*256]   110,493,696 B   ([t][chan][b])
    //   Abf bf16 [M_TOT*288]      41,435,136 B   (H1fin aliases: dead after gemm)
    //   Wt0 bf16 [3*128*288]         221,184 B
    //   Wh0/Wx1/Wh1 bf16 [384*128]    98,304 B each
    char* ws = (char*)d_ws;
    float*          XG    = (float*)ws;
    unsigned short* Abf   = (unsigned short*)(ws + (size_t)M_TOT * 384 * 4);
    float*          H1fin = (float*)Abf;        // alias: Abf dead after gemm_xg
    unsigned short* Wt0   = (unsigned short*)(ws + (size_t)M_TOT * 384 * 4 + (size_t)M_TOT * KPAD0 * 2);
    unsigned short* Wh0   = Wt0 + (size_t)3 * HID * KPAD0;
    unsigned short* Wx1   = Wh0 + (size_t)384 * HID;
    unsigned short* Wh1   = Wx1 + (size_t)384 * HID;

    wt_kernel<<<dim3(12, 32), 256, 0, stream>>>(Wr0, Wu0, Wo0, Wr1, Wu1, Wo1,
                                                Wt0, Wh0, Wx1, Wh1);
    xt_kernel<<<dim3(5, BATCH), 256, 0, stream>>>(X, Abf);
    gemm_xg  <<<dim3(M_TOT / 128, 3), 256, 0, stream>>>(Abf, Wt0, br0, bu0, bo0, XG);
    gru_fused<<<dim3(16), 512, 0, stream>>>(Wh0, Wx1, Wh1, XG, br1, bu1, bo1, H1fin);
    cls_kernel<<<dim3(64), 256, 0, stream>>>(H1fin, Wfc, bfc, out);
}